// Round 7
// baseline (49.388 us; speedup 1.0000x reference)
//
#include <hip/hip_runtime.h>
#include <hip/hip_bf16.h>

typedef _Float16 half8 __attribute__((ext_vector_type(8)));
typedef _Float16 half4v __attribute__((ext_vector_type(4)));
typedef float f32x4 __attribute__((ext_vector_type(4)));

#define NCOLS 176               // 48 (padded 36-group) + 128
#define TILE_ELEMS (NCOLS*32)   // 5632 f16 per K-step tile
#define TILE_U16 (TILE_ELEMS/8) // 704 uint4 units
#define WTSTR 40                // pack LDS pad
#define BM 16
#define XPN_OFF (1u<<20)        // Xpn at ws+1MB (Wp occupies first 811008 B)

// ---- gemm_tail LDS layout (tail only; no X staging in LDS) ----
#define OFF_A36 0        // [16][40] f32  = 2560
#define OFF_TQ  2560     // [16][128] f32 = 8192
#define OFF_TPN 10752    // [16][128] f32 = 8192
#define OFF_WV  18944    // [16] f32 pad64
#define OFF_X1  19008    // [16][132] f32 = 8448
#define OFF_W2  27456    // [128][64] f16 = 16384
#define OFF_X2  43840    // [16][68] f32  = 4352
#define OFF_W3  48192    // [64][24] f16  = 3072
#define OFF_X3  51264    // [16][28] f32  = 1792 -> 53056
#define OFF_SCR 53056    // 2-way K reduce scratch: 24 * 256 f32 = 24576
#define SM_BYTES 77632

struct Params {
  const float *qid, *node, *leaf;
  const int *pos_idx, *neg_idx, *p_leaf, *n_leaf;
  const float *W00, *W1;
  const float *b00, *a00, *W01, *b01;
  const float *b1, *a1, *g1, *be1, *m1, *v1;
  const float *W2, *b2, *a2, *g2, *be2, *m2, *v2;
  const float *W3, *b3, *a3, *g3, *be3, *m3, *v3;
  const float *W4, *b4;
  _Float16 *Wp;          // ws + 0
  _Float16 *Xpn;         // ws + 1MB: [4096][2][768] f16 (pos|neg)
  float *out;
};

// K_prep: blocks 0..71 pack weights (f16, [g][col][32k]); blocks 72..1095
// gather pos/neg embedding rows -> f16 Xpn at full-grid TLP.
__global__ __launch_bounds__(256) void prep(Params p) {
  const int b = blockIdx.x;
  const int tid = threadIdx.x;
  if (b < 72) {
    int g = b;
    int s = g / 24, t = g - s * 24;
    int k0 = t * 32;
    int w1row0 = (s == 0) ? 1536 : (s == 1 ? 0 : 768);
    __shared__ _Float16 T[NCOLS][WTSTR];
    for (int u = tid; u < 1024; u += 256) {          // W1 part
      int kk = u >> 5, c4 = u & 31;
      float4 f = *(const float4*)(p.W1 + (size_t)(w1row0 + k0 + kk) * 128 + c4 * 4);
      int c = 48 + c4 * 4;
      T[c + 0][kk] = (_Float16)f.x; T[c + 1][kk] = (_Float16)f.y;
      T[c + 2][kk] = (_Float16)f.z; T[c + 3][kk] = (_Float16)f.w;
    }
    for (int u = tid; u < 1152; u += 256) {          // W00 part
      int kk = u / 36, c = u - kk * 36;
      T[c][kk] = (_Float16)p.W00[(size_t)(s * 768 + k0 + kk) * 36 + c];
    }
    for (int u = tid; u < 384; u += 256) {           // zero pad cols 36..47
      int kk = u & 31, c = 36 + (u >> 5);
      T[c][kk] = (_Float16)0.f;
    }
    __syncthreads();
    uint4* dst = (uint4*)(p.Wp + (size_t)g * TILE_ELEMS);
    for (int u = tid; u < TILE_U16; u += 256) {
      int c = u >> 2, q = u & 3;
      dst[u] = *(const uint4*)&T[c][q * 8];
    }
  } else {
    // gather: 786432 chunks of 8 f32 -> 8 f16; chunk id -> (sample, seg, c4)
    int gb = b - 72;                   // 0..1023
#pragma unroll
    for (int j = 0; j < 3; ++j) {
      int id = gb * 256 + tid + j * 262144;
      int s  = id / 192;
      int r  = id - s * 192;
      int seg = r / 96;
      int c4  = r - seg * 96;
      int idx = (seg == 0 ? p.pos_idx : p.neg_idx)[s];
      int lf  = (seg == 0 ? p.p_leaf  : p.n_leaf )[s];
      const float* src = ((lf == 1) ? p.leaf : p.node) + (size_t)idx * 768 + c4 * 8;
      float4 fa = *(const float4*)src;
      float4 fb = *(const float4*)(src + 4);
      half8 h = { (_Float16)fa.x, (_Float16)fa.y, (_Float16)fa.z, (_Float16)fa.w,
                  (_Float16)fb.x, (_Float16)fb.y, (_Float16)fb.z, (_Float16)fb.w };
      *(half8*)(p.Xpn + (size_t)s * 1536 + seg * 768 + c4 * 8) = h;
    }
  }
}

// K_gemm: 512 thr = 8 waves (nw = wid&3 col group, kg = wid>>2 K parity).
// Zero-barrier K-loop: A fragments stream straight from global (qid f32 for
// t<12, Xpn f16 after), W fragments from packed Wp; 6-deep A / 4-deep W
// register pipelines; first barrier is the reduction. Tail = R4 (proven).
__global__ __launch_bounds__(512) void gemm_tail(Params p) {
  __shared__ __align__(16) char sm[SM_BYTES];
  float*    A36 = (float*)(sm + OFF_A36);
  float*    Tq  = (float*)(sm + OFF_TQ);
  float*    Tpn = (float*)(sm + OFF_TPN);
  float*    wv  = (float*)(sm + OFF_WV);
  float*    x1  = (float*)(sm + OFF_X1);
  _Float16* W2h = (_Float16*)(sm + OFF_W2);
  float*    x2  = (float*)(sm + OFF_X2);
  _Float16* W3h = (_Float16*)(sm + OFF_W3);
  float*    x3  = (float*)(sm + OFF_X3);
  float*    scr = (float*)(sm + OFF_SCR);

  const int tid  = threadIdx.x;
  const int wid  = tid >> 6;
  const int lane = tid & 63;
  const int lm   = lane & 15;
  const int hk   = lane >> 4;
  const int nw   = wid & 3;
  const int kg   = wid >> 2;              // 0/1
  const int m0   = blockIdx.x * BM;
  const bool HAS2 = (nw < 3);

  const float*     qrow = p.qid + (size_t)(m0 + lm) * 768;
  const _Float16*  xrow = p.Xpn + (size_t)(m0 + lm) * 1536;

  const uint4* Wp4 = (const uint4*)p.Wp;
  const int woff = ((nw * 48 + lm) << 2) + hk;

  uint4 P[4][3];
  auto ldWp = [&](int t) {                // tile g = kg + 2t
    const uint4* b = Wp4 + (size_t)(kg + 2 * t) * TILE_U16 + woff;
    P[t & 3][0] = b[0]; P[t & 3][1] = b[64];
    if (HAS2) P[t & 3][2] = b[128];
  };

  half8 av[6];
  // ldA: tile g = kg+2t; t<12 <=> seg0 (q, f32->f16 inline); else Xpn f16.
#define LDA(t) ( (t) < 12 ? ({ \
      const float* s_ = qrow + (kg + 2*(t)) * 32 + hk * 8; \
      float4 fa_ = *(const float4*)s_; \
      float4 fb_ = *(const float4*)(s_ + 4); \
      half8 h_ = { (_Float16)fa_.x, (_Float16)fa_.y, (_Float16)fa_.z, (_Float16)fa_.w, \
                   (_Float16)fb_.x, (_Float16)fb_.y, (_Float16)fb_.z, (_Float16)fb_.w }; h_; }) \
    : *(const half8*)(xrow + (kg + 2*(t) - 24) * 32 + hk * 8) )

  f32x4 accA[3] = {{0.f,0.f,0.f,0.f},{0.f,0.f,0.f,0.f},{0.f,0.f,0.f,0.f}};
  f32x4 accB[3] = {{0.f,0.f,0.f,0.f},{0.f,0.f,0.f,0.f},{0.f,0.f,0.f,0.f}};

  // prologue: 12 W loads + 6 A fragments, all independent, no barriers
  ldWp(0); ldWp(1); ldWp(2); ldWp(3);
  av[0] = LDA(0); av[1] = LDA(1); av[2] = LDA(2);
  av[3] = LDA(3); av[4] = LDA(4); av[5] = LDA(5);

#pragma unroll
  for (int t = 0; t < 36; ++t) {
    half8 a  = av[t % 6];
    half8 b0 = __builtin_bit_cast(half8, P[t & 3][0]);
    half8 b1 = __builtin_bit_cast(half8, P[t & 3][1]);
    half8 b2 = __builtin_bit_cast(half8, P[t & 3][2]);
    if ((nw == 0) || (t < 12)) {
      accA[0] = __builtin_amdgcn_mfma_f32_16x16x32_f16(a, b0, accA[0], 0, 0, 0);
      accA[1] = __builtin_amdgcn_mfma_f32_16x16x32_f16(a, b1, accA[1], 0, 0, 0);
      if (HAS2) accA[2] = __builtin_amdgcn_mfma_f32_16x16x32_f16(a, b2, accA[2], 0, 0, 0);
    } else {
      accB[0] = __builtin_amdgcn_mfma_f32_16x16x32_f16(a, b0, accB[0], 0, 0, 0);
      accB[1] = __builtin_amdgcn_mfma_f32_16x16x32_f16(a, b1, accB[1], 0, 0, 0);
      if (HAS2) accB[2] = __builtin_amdgcn_mfma_f32_16x16x32_f16(a, b2, accB[2], 0, 0, 0);
    }
    if (t + 4 < 36) ldWp(t + 4);
    if (t + 6 < 36) av[t % 6] = LDA(t + 6);
  }

  // issue tail W2 loads (land during reduction)
  float4 w2r[4];
#pragma unroll
  for (int jj = 0; jj < 4; ++jj) w2r[jj] = ((const float4*)p.W2)[tid + jj * 512];

  // ---- K-parity reduction (first barriers of the kernel) ----
  if (kg == 1) {
#pragma unroll
    for (int n = 0; n < 3; ++n) {
      if (n < 2 || HAS2) {
#pragma unroll
        for (int r = 0; r < 4; ++r) {
          int base = ((nw * 3 + n) * 2) * 256 + (hk * 4 + r) * 16 + lm;
          scr[base]       = accA[n][r];
          scr[base + 256] = accB[n][r];
        }
      }
    }
  }
  __syncthreads();
  if (kg == 0) {
#pragma unroll
    for (int n = 0; n < 3; ++n) {
      if (n < 2 || HAS2) {
#pragma unroll
        for (int r = 0; r < 4; ++r) {
          int base = ((nw * 3 + n) * 2) * 256 + (hk * 4 + r) * 16 + lm;
          float va = accA[n][r] + scr[base];
          float vb = accB[n][r] + scr[base + 256];
          int row = hk * 4 + r;
          int col = nw * 48 + n * 16 + lm;
          if (nw == 0) { if (col < 36) A36[row * 40 + col] = va; }
          else { int rc = col - 48; Tq[row * 128 + rc] = va; Tpn[row * 128 + rc] = vb; }
        }
      }
    }
  }
  __syncthreads();

  // ---- fused tail (R4, verified) ----
#pragma unroll
  for (int jj = 0; jj < 4; ++jj) {
    int u = tid + jj * 512;                // 2048 float4 = 128*64/4
    float4 f = w2r[jj];
    half4v h = { (_Float16)f.x, (_Float16)f.y, (_Float16)f.z, (_Float16)f.w };
    *(half4v*)(W2h + (u >> 4) * 64 + (u & 15) * 4) = h;
  }
  if (tid < BM) {
    float acc = p.b01[0];
    for (int c = 0; c < 36; ++c) {
      float h = A36[tid * 40 + c] + p.b00[c];
      h = (h > 0.f) ? h : p.a00[c] * h;
      acc += h * p.W01[c];
    }
    wv[tid] = acc;
  }
  __syncthreads();

#pragma unroll
  for (int j = 0; j < 4; ++j) {
    int u = tid + j * 512;                 // 2048 = 16*128
    int i = u >> 7, c = u & 127;
    float v = wv[i] * Tpn[i * 128 + c] + Tq[i * 128 + c] + p.b1[c];
    v = (v > 0.f) ? v : p.a1[c] * v;
    v = (v - p.m1[c]) * (1.f / sqrtf(p.v1[c] + 1e-3f)) * p.g1[c] + p.be1[c];
    x1[i * 132 + c] = v;
  }
  __syncthreads();

  if (tid < 256) {
    int i = tid & 15, cq = tid >> 4;
    const float* xr = x1 + i * 132;
    f32x4 acc0 = { p.b2[cq*4+0], p.b2[cq*4+1], p.b2[cq*4+2], p.b2[cq*4+3] };
    f32x4 acc1 = { 0.f, 0.f, 0.f, 0.f };
#pragma unroll 8
    for (int k = 0; k < 128; k += 2) {
      half4v w0 = *(const half4v*)(W2h + k * 64 + cq * 4);
      half4v w1 = *(const half4v*)(W2h + (k + 1) * 64 + cq * 4);
      acc0 += xr[k]     * __builtin_convertvector(w0, f32x4);
      acc1 += xr[k + 1] * __builtin_convertvector(w1, f32x4);
    }
    f32x4 acc = acc0 + acc1;
#pragma unroll
    for (int jj = 0; jj < 4; ++jj) {
      int c = cq * 4 + jj;
      float v = acc[jj];
      v = (v > 0.f) ? v : p.a2[c] * v;
      v = (v - p.m2[c]) * (1.f / sqrtf(p.v2[c] + 1e-3f)) * p.g2[c] + p.be2[c];
      x2[i * 68 + c] = v;
    }
  }
  for (int j = 0; j < 3; ++j) {            // stage W3 f16 (flat 1536)
    int u = tid + j * 512;
    if (u < 1536) W3h[u] = (_Float16)p.W3[u];
  }
  __syncthreads();

  if (tid < 384) {
    int i = tid & 15, c = tid >> 4;
    float acc = p.b3[c];
#pragma unroll 8
    for (int k = 0; k < 64; ++k) acc += x2[i * 68 + k] * (float)W3h[k * 24 + c];
    acc = (acc > 0.f) ? acc : p.a3[c] * acc;
    acc = (acc - p.m3[c]) * (1.f / sqrtf(p.v3[c] + 1e-3f)) * p.g3[c] + p.be3[c];
    x3[i * 28 + c] = acc;
  }
  __syncthreads();

  if (tid < BM) {
    float l0 = p.b4[0], l1 = p.b4[1];
#pragma unroll
    for (int k = 0; k < 24; ++k) {
      float v = x3[tid * 28 + k];
      l0 += v * p.W4[k * 2 + 0];
      l1 += v * p.W4[k * 2 + 1];
    }
    float m = fmaxf(l0, l1);
    float e0 = __expf(l0 - m), e1 = __expf(l1 - m);
    float inv = 1.f / (e0 + e1);
    p.out[(size_t)(m0 + tid) * 2 + 0] = e0 * inv;
    p.out[(size_t)(m0 + tid) * 2 + 1] = e1 * inv;
  }
}

extern "C" void kernel_launch(void* const* d_in, const int* in_sizes, int n_in,
                              void* d_out, int out_size, void* d_ws, size_t ws_size,
                              hipStream_t stream) {
  Params p;
  p.qid  = (const float*)d_in[0];
  p.node = (const float*)d_in[1];
  p.leaf = (const float*)d_in[2];
  p.pos_idx = (const int*)d_in[3];
  p.neg_idx = (const int*)d_in[4];
  p.p_leaf  = (const int*)d_in[5];
  p.n_leaf  = (const int*)d_in[6];
  p.W00 = (const float*)d_in[7];
  p.b00 = (const float*)d_in[8];
  p.a00 = (const float*)d_in[9];
  p.W01 = (const float*)d_in[10];
  p.b01 = (const float*)d_in[11];
  p.W1  = (const float*)d_in[12];
  p.b1  = (const float*)d_in[13];
  p.a1  = (const float*)d_in[14];
  p.g1  = (const float*)d_in[15];
  p.be1 = (const float*)d_in[16];
  p.m1  = (const float*)d_in[17];
  p.v1  = (const float*)d_in[18];
  p.W2  = (const float*)d_in[19];
  p.b2  = (const float*)d_in[20];
  p.a2  = (const float*)d_in[21];
  p.g2  = (const float*)d_in[22];
  p.be2 = (const float*)d_in[23];
  p.m2  = (const float*)d_in[24];
  p.v2  = (const float*)d_in[25];
  p.W3  = (const float*)d_in[26];
  p.b3  = (const float*)d_in[27];
  p.a3  = (const float*)d_in[28];
  p.g3  = (const float*)d_in[29];
  p.be3 = (const float*)d_in[30];
  p.m3  = (const float*)d_in[31];
  p.v3  = (const float*)d_in[32];
  p.W4  = (const float*)d_in[33];
  p.b4  = (const float*)d_in[34];
  p.Wp  = (_Float16*)d_ws;
  p.Xpn = (_Float16*)((char*)d_ws + XPN_OFF);
  p.out = (float*)d_out;

  prep<<<1096, 256, 0, stream>>>(p);
  int B = in_sizes[3];              // 4096
  gemm_tail<<<B / BM, 512, 0, stream>>>(p);
}